// Round 14
// baseline (86.782 us; speedup 1.0000x reference)
//
#include <hip/hip_runtime.h>
#include <math.h>

#define NC      128   // data columns
#define NSTATE  256   // n_dist_support
#define NITERS  33
#define NSTEPS  6
#define RPB     2     // rows per block; each row = 2 waves (redundant diffusion)
#define LN2     (0.6931471805599453f)

#define DPP_WAVE_SHL1 0x130   // lane l <- lane l+1 (bound_ctrl: lane63 -> 0)
#define DPP_WAVE_SHR1 0x138   // lane l <- lane l-1 (bound_ctrl: lane0  -> 0)

__device__ __forceinline__ float dpp_shr1(float x) {   // value from lane-1, 0 at lane 0
    return __int_as_float(__builtin_amdgcn_update_dpp(
        0, __float_as_int(x), DPP_WAVE_SHR1, 0xf, 0xf, true));
}
__device__ __forceinline__ float dpp_shl1(float x) {   // value from lane+1, 0 at lane 63
    return __int_as_float(__builtin_amdgcn_update_dpp(
        0, __float_as_int(x), DPP_WAVE_SHL1, 0xf, 0xf, true));
}

// TWO waves per row (8192 waves -> ~28 resident waves/CU). Both waves of a row
// run the IDENTICAL register diffusion, but each wave owns PRIVATE LDS slices
// (round 13's cross-wave same-address LDS write race caused absmax 7.64 —
// never share LDS between unsynchronized waves, even with identical data).
// Matching split: h=0 -> shifts 0..63 + 128, h=1 -> shifts 64..127.
// Combine via red_s + one __syncthreads.
__global__ __launch_bounds__(256, 8)
void tonal_diffusion_kernel(const float* __restrict__ data,
                            const float* __restrict__ logw,
                            float* __restrict__ out, int n_rows)
{
    const int tid  = threadIdx.x;
    const int wid  = tid >> 6;          // 0..3
    const int lane = tid & 63;
    const int rib  = wid >> 1;          // row within block: 0,1
    const int h    = wid & 1;           // half-duty: 0 or 1
    int row = blockIdx.x * RPB + rib;
    row = row < n_rows ? row : n_rows - 1;   // uniform clamp (dup rows benign)
    const int urow = __builtin_amdgcn_readfirstlane(row);

    // PER-WAVE private LDS (indexed by wid — no cross-wave sharing anywhere)
    __shared__ __align__(16) float licdR_s[4][4][NSTATE]; // [wave][rot copy][state]
    __shared__ __align__(16) float P_s    [4][NSTATE];    // [wave][state]
    __shared__ float red_s[RPB][2];
    float (* __restrict__ licdR)[NSTATE] = licdR_s[wid];
    float * __restrict__ P               = P_s[wid];

    const float* __restrict__ drow = data + (size_t)urow * NC;  // uniform pointer

    // ---- weights: w = exp(lw); rate = sum w; p = w/rate  (steps {1,-1,-3,3,4,-4})
    float rate, p0, p1, p2, p3, p4, p5;
    {
        const float* lw = logw + urow * NSTEPS;
        p0 = __expf(lw[0]); p1 = __expf(lw[1]); p2 = __expf(lw[2]);
        p3 = __expf(lw[3]); p4 = __expf(lw[4]); p5 = __expf(lw[5]);
        rate = ((p0 + p1) + (p2 + p3)) + (p4 + p5);
        const float inv = 1.0f / rate;
        p0 *= inv; p1 *= inv; p2 *= inv; p3 *= inv; p4 *= inv; p5 *= inv;
    }

    // ---- per-lane data (cols 2*lane, 2*lane+1): plogp with zero-guard
    const float2 dl = *(const float2*)(drow + 2 * lane);
    float plogp;
    {
        float pl = 0.f;
        if (dl.x > 1e-8f) pl += dl.x * __logf(dl.x);   // isclose(data,0) excluded
        if (dl.y > 1e-8f) pl += dl.y * __logf(dl.y);
        #pragma unroll
        for (int off = 1; off < 64; off <<= 1) pl += __shfl_xor(pl, off, 64);
        plogp = pl;
    }

    // ---- Poisson-weighted diffusion, registers only; neighbors via DPP (no DS)
    float r0 = 0.f, r1 = 0.f, r2 = 0.f, r3 = 0.f;
    if (lane == 32) r0 = 1.0f;                 // center state 128 = 4*32+0
    float a0 = 0.f, a1 = 0.f, a2 = 0.f, a3 = 0.f;
    float sp = __expf(-rate);                  // Poisson pmf(0)
    #pragma unroll
    for (int n = 0; n < NITERS; ++n) {
        a0 += sp * r0; a1 += sp * r1; a2 += sp * r2; a3 += sp * r3;
        const float L0 = dpp_shr1(r0), L1 = dpp_shr1(r1),
                    L2 = dpp_shr1(r2), L3 = dpp_shr1(r3);   // lane-1 (0 at edge)
        const float R0 = dpp_shl1(r0), R1 = dpp_shl1(r1),
                    R2 = dpp_shl1(r2), R3 = dpp_shl1(r3);   // lane+1 (0 at edge)
        // new[t] = sum_i p[i]*cur[t-steps[i]] ; t = 4*lane + j
        const float n0 = p0*L3 + p1*r1 + p2*r3 + p3*L1 + p4*L0 + p5*R0;
        const float n1 = p0*r0 + p1*r2 + p2*R0 + p3*L2 + p4*L1 + p5*R1;
        const float n2 = p0*r1 + p1*r3 + p2*R1 + p3*L3 + p4*L2 + p5*R2;
        const float n3 = p0*r2 + p1*R0 + p2*R2 + p3*r0 + p4*L3 + p5*R3;
        r0 = n0; r1 = n1; r2 = n2; r3 = n3;
        sp = sp * rate * (1.0f / (float)(n + 1));     // folds under full unroll
    }

    // ---- licd = log2(raw acc); 4 rotated copies, aligned b128 stores (private)
    {
        const float l0 = __log2f(a0), l1 = __log2f(a1),
                    l2 = __log2f(a2), l3 = __log2f(a3);
        const float nl0 = dpp_shl1(l0), nl1 = dpp_shl1(l1), nl2 = dpp_shl1(l2);
        *(float4*)&licdR[0][4 * lane] = make_float4(l0, l1, l2, l3);
        *(float4*)&licdR[1][4 * lane] = make_float4(l1, l2, l3, nl0);
        *(float4*)&licdR[2][4 * lane] = make_float4(l2, l3, nl0, nl1);
        *(float4*)&licdR[3][4 * lane] = make_float4(l3, nl0, nl1, nl2);
    }

    // ---- inclusive prefix sum P of raw acc (in-lane serial + wave scan)
    {
        const float s0 = a0, s1 = s0 + a1, s2 = s1 + a2, s3 = s2 + a3;
        float t = s3;
        #pragma unroll
        for (int off = 1; off < 64; off <<= 1) {
            const float u = __shfl_up(t, off, 64);
            if (lane >= off) t += u;
        }
        const float base = t - s3;
        *(float4*)&P[4 * lane] = make_float4(base + s0, base + s1, base + s2, base + s3);
    }

    // ---- matching, split by h. loss2(s) = log2(Z_s) - dot(d, licd[s:s+128]).
    const int phi = lane & 3;
    const float* __restrict__ lcp = &licdR[phi][lane - phi];   // 16B-aligned per lane
    float best2;
    if (h == 0) {
        // shift sA = lane
        const float zA2 = __log2f(P[lane + 127] - (lane ? P[lane - 1] : 0.f));
        float dotA = 0.f;
        #pragma unroll 2
        for (int j = 0; j < 16; ++j) {
            const float4 L1v = *(const float4*)(lcp + 4 * j);        // licd[lane+4j]
            const float4 L2v = *(const float4*)(lcp + 4 * j + 64);   // licd[lane+64+4j]
            const float4 dLo = *(const float4*)(drow + 4 * j);       // uniform
            const float4 dHi = *(const float4*)(drow + 4 * j + 64);  // uniform
            dotA += dLo.x * L1v.x; dotA += dLo.y * L1v.y;
            dotA += dLo.z * L1v.z; dotA += dLo.w * L1v.w;
            dotA += dHi.x * L2v.x; dotA += dHi.y * L2v.y;
            dotA += dHi.z * L2v.z; dotA += dHi.w * L2v.w;
        }
        best2 = zA2 - dotA;
        // shift 128: distributed 2 cols/lane + wave reduce
        const float z2 = __log2f(P[255] - P[127]);
        const float2 lv = *(const float2*)(&licdR[0][128 + 2 * lane]);
        float part = dl.x * lv.x + dl.y * lv.y;
        #pragma unroll
        for (int off = 1; off < 64; off <<= 1) part += __shfl_xor(part, off, 64);
        best2 = fminf(best2, z2 - part);
    } else {
        // shift sB = 64 + lane
        const float zB2 = __log2f(P[lane + 191] - P[lane + 63]);
        float dotB = 0.f;
        #pragma unroll 2
        for (int j = 0; j < 16; ++j) {
            const float4 L2v = *(const float4*)(lcp + 4 * j + 64);   // licd[lane+64+4j]
            const float4 L3v = *(const float4*)(lcp + 4 * j + 128);  // licd[lane+128+4j]
            const float4 dLo = *(const float4*)(drow + 4 * j);       // uniform
            const float4 dHi = *(const float4*)(drow + 4 * j + 64);  // uniform
            dotB += dLo.x * L2v.x; dotB += dLo.y * L2v.y;
            dotB += dLo.z * L2v.z; dotB += dLo.w * L2v.w;
            dotB += dHi.x * L3v.x; dotB += dHi.y * L3v.y;
            dotB += dHi.z * L3v.z; dotB += dHi.w * L3v.w;
        }
        best2 = zB2 - dotB;
    }

    // ---- wave min; combine the row's two waves via LDS + one barrier
    #pragma unroll
    for (int off = 1; off < 64; off <<= 1) best2 = fminf(best2, __shfl_xor(best2, off, 64));
    if (lane == 0) red_s[rib][h] = best2;
    __syncthreads();
    if (lane == 0 && h == 0)
        out[row] = plogp + LN2 * fminf(red_s[rib][0], red_s[rib][1]);
}

extern "C" void kernel_launch(void* const* d_in, const int* in_sizes, int n_in,
                              void* d_out, int out_size, void* d_ws, size_t ws_size,
                              hipStream_t stream)
{
    const float* data = (const float*)d_in[0];   // [n, 128] f32
    const float* logw = (const float*)d_in[1];   // [n, 6]   f32
    float* out = (float*)d_out;                  // [n]      f32
    const int n_rows = in_sizes[0] / NC;
    const int blocks = (n_rows + RPB - 1) / RPB;
    tonal_diffusion_kernel<<<blocks, 256, 0, stream>>>(data, logw, out, n_rows);
}